// Round 11
// baseline (193.733 us; speedup 1.0000x reference)
//
#include <hip/hip_runtime.h>
#include <hip/hip_bf16.h>

#define HW 2304          // 48*48
#define HW2 4608         // HW * sizeof(bf16)
#define NB 8             // batch
#define NC 256           // input channels
#define HID 128          // heads*dim_head
#define DH 32            // dim_head
#define NH 4             // heads
#define SCALE 0.17677669529663687f   // 1/sqrt(32)
#define LOG2E 1.4426950408889634f
#define LN2   0.6931471805599453f

#define NSPLIT 4         // flash split-K factor
#define OSZ ((size_t)NB * HW * HID)   // one O-partial

using bf16x8 = __attribute__((ext_vector_type(8))) short;
using f32x4  = __attribute__((ext_vector_type(4))) float;

__device__ __forceinline__ short f2bf(float f) {   // RNE float->bf16
    unsigned u = __float_as_uint(f);
    u += 0x7FFF + ((u >> 16) & 1);
    return (short)(u >> 16);
}
__device__ __forceinline__ float bf2f(short s) {
    return __uint_as_float(((unsigned)(unsigned short)s) << 16);
}
__device__ __forceinline__ unsigned pk2bf(float a, float b) {  // pack 2 bf16 (RNE)
    union { __hip_bfloat162 h; unsigned u; } cv;
    cv.h = __float22bfloat162_rn(float2{a, b});
    return cv.u;
}
__device__ __forceinline__ void gld16(const void* g, void* l) {  // 16B global->LDS DMA
    __builtin_amdgcn_global_load_lds(
        (const __attribute__((address_space(1))) unsigned*)g,
        (__attribute__((address_space(3))) unsigned*)l, 16, 0, 0);
}
#define SB() __builtin_amdgcn_sched_barrier(0)

// ---------------------------------------------------------------------------
// Fused pre-pass, VECTORIZED (r10). z<8: x [b][256][2304] fp32 ->
// Xt [b][2304][256] bf16 via 64x64 tiles: float4 coalesced reads (16B/lane),
// bf16 LDS tile [64 s][72 c], bf16x8 aligned stores (16B/lane).
// z==8: weight fp32->bf16 conversion (sweep loop) + zero E/ticket words.
// ---------------------------------------------------------------------------
__global__ __launch_bounds__(256)
void prep(const float* __restrict__ x, const float* __restrict__ wq,
          const float* __restrict__ wo, short* __restrict__ Xt,
          short* __restrict__ Wq, short* __restrict__ Wo, float* __restrict__ wsz)
{
    if (blockIdx.z == 8) {
        const int bid = blockIdx.x + 36 * blockIdx.y;   // 0..143
        if (bid == 0 && threadIdx.x == 0) { wsz[0] = 0.f; ((int*)wsz)[1] = 0; }
        for (int i = bid * 256 + threadIdx.x; i < 384 * 256; i += 144 * 256) {
            Wq[i] = f2bf(wq[i]);
            if (i < 256 * 128) Wo[i] = f2bf(wo[i]);
        }
        return;
    }
    __shared__ short Tb[64][72];                 // bf16 [s][c], pad 72
    const int b = blockIdx.z, c0 = blockIdx.y * 64, s0 = blockIdx.x * 64;
    const int ts4 = (threadIdx.x & 15) * 4;      // 4 s per thread
    const int cc0 = threadIdx.x >> 4;            // 16 c rows per pass
    #pragma unroll
    for (int pp = 0; pp < 4; ++pp) {
        const int cc = cc0 + pp * 16;
        const float4 v = *(const float4*)(
            x + ((size_t)b * NC + c0 + cc) * HW + s0 + ts4);
        Tb[ts4 + 0][cc] = f2bf(v.x);
        Tb[ts4 + 1][cc] = f2bf(v.y);
        Tb[ts4 + 2][cc] = f2bf(v.z);
        Tb[ts4 + 3][cc] = f2bf(v.w);
    }
    __syncthreads();
    const int ss = threadIdx.x >> 2;             // 64 s
    const int c8 = (threadIdx.x & 3) * 8;        // c octet
    #pragma unroll
    for (int pp = 0; pp < 2; ++pp) {
        const int cc = c8 + pp * 32;
        const bf16x8 v = *(const bf16x8*)&Tb[ss][cc];
        *(bf16x8*)(Xt + ((size_t)b * HW + s0 + ss) * NC + c0 + cc) = v;
    }
}

// ---------------------------------------------------------------------------
// QKV MFMA 1x1-conv GEMM, r11: BK=64 (4 chunks of 64-K, was 8x32-K) -- half
// the barriers/vmcnt/stage events per unit work, 16 MFMA/wave per barrier.
// Chunk buffer = two 32-K units of 12KB (A 4KB | B 8KB each); ring-2 (48KB),
// flash-proven minimal 2-phase: [vmcnt(0); barrier; stage next; compute 2
// sub-units]. Epilogue unchanged: Q(xSCALE*LOG2E); K sigma-permuted
// (sigma(g)=((g&4)<<2)|((g>>3)<<2)|(g&3)) + Kt [bh][dh][s]; V [bh][dh][s].
// ---------------------------------------------------------------------------
__global__ __launch_bounds__(256, 2)
void conv_qkv(const short* __restrict__ A, const short* __restrict__ Bt,
              const float* __restrict__ bias,
              short* __restrict__ Qb, short* __restrict__ Kb,
              short* __restrict__ Kt, short* __restrict__ Vb,
              float* __restrict__ E)
{
    constexpr int KD = NC;
    constexpr int NI = KD / 64;                 // 4 chunks of 64-K
    const int b  = blockIdx.z;
    const int bm = blockIdx.y * 64;
    const int bn = blockIdx.x * 128;
    const int t  = threadIdx.x;
    const int w  = t >> 6, lane = t & 63;
    const int n16 = lane & 15, quad = lane >> 4;

    __shared__ __align__(16) char csm[2 * 24576];   // ring-2 x 64-K chunk (24KB)
    __shared__ float red[4];

    const int rL = lane >> 2, cswz = (lane & 3) ^ (rL & 3);
    const char* agl = (const char*)(A  + (size_t)(bm + rL) * KD + cswz * 8);
    const char* bgl = (const char*)(Bt + ((size_t)b * HW + bn + rL) * KD + cswz * 8);

    auto issue32 = [&](int kc, char* base) {    // one 32-K unit, 3 gld16/wave
        if (w == 0) {
            gld16(agl + (size_t)(0 * 16 * KD + kc) * 2, base + 0 * 1024);
            gld16(agl + (size_t)(1 * 16 * KD + kc) * 2, base + 1 * 1024);
            gld16(bgl + (size_t)(0 * 16 * KD + kc) * 2, base + 4096 + 0 * 1024);
        } else if (w == 1) {
            gld16(agl + (size_t)(2 * 16 * KD + kc) * 2, base + 2 * 1024);
            gld16(agl + (size_t)(3 * 16 * KD + kc) * 2, base + 3 * 1024);
            gld16(bgl + (size_t)(1 * 16 * KD + kc) * 2, base + 4096 + 1 * 1024);
        } else if (w == 2) {
            gld16(bgl + (size_t)(2 * 16 * KD + kc) * 2, base + 4096 + 2 * 1024);
            gld16(bgl + (size_t)(3 * 16 * KD + kc) * 2, base + 4096 + 3 * 1024);
            gld16(bgl + (size_t)(4 * 16 * KD + kc) * 2, base + 4096 + 4 * 1024);
        } else {
            gld16(bgl + (size_t)(5 * 16 * KD + kc) * 2, base + 4096 + 5 * 1024);
            gld16(bgl + (size_t)(6 * 16 * KD + kc) * 2, base + 4096 + 6 * 1024);
            gld16(bgl + (size_t)(7 * 16 * KD + kc) * 2, base + 4096 + 7 * 1024);
        }
    };
    auto stage = [&](int kc, int pbuf) {        // 64-K chunk, 6 gld16/wave
        issue32(kc,      csm + pbuf * 24576);
        issue32(kc + 32, csm + pbuf * 24576 + 12288);
    };

    f32x4 acc[4][2] = {};
    const int rsw = (quad ^ (n16 & 3)) * 16;    // frag-read swizzle (bytes)

    stage(0, 0); SB();
    for (int ki = 0; ki < NI; ++ki) {
        const int p = ki & 1;
        asm volatile("s_waitcnt vmcnt(0)" ::: "memory");   // stage(ki) landed (aged 1 phase)
        __builtin_amdgcn_s_barrier();
        SB();
        if (ki + 1 < NI) stage((ki + 1) * 64, p ^ 1);      // overwrites buf read at ki-1

        #pragma unroll
        for (int su = 0; su < 2; ++su) {
            const char* Ap = csm + p * 24576 + su * 12288;
            const char* Bp = Ap + 4096;
            bf16x8 am[4], bq[2];
            #pragma unroll
            for (int tm = 0; tm < 4; ++tm)
                am[tm] = *(const bf16x8*)(Ap + tm * 1024 + n16 * 64 + rsw);
            #pragma unroll
            for (int j = 0; j < 2; ++j)
                bq[j] = *(const bf16x8*)(Bp + (w * 2 + j) * 1024 + n16 * 64 + rsw);
            #pragma unroll
            for (int tm = 0; tm < 4; ++tm)
                #pragma unroll
                for (int j = 0; j < 2; ++j)
                    acc[tm][j] = __builtin_amdgcn_mfma_f32_16x16x32_bf16(am[tm], bq[j], acc[tm][j], 0, 0, 0);
        }
    }

    float e = 0.f;
    #pragma unroll
    for (int tm = 0; tm < 4; ++tm) {
        const int o0 = bm + tm * 16 + quad * 4;
        const float4 bb = *(const float4*)(bias + o0);
        #pragma unroll
        for (int j = 0; j < 2; ++j) {
            const int s = bn + (w * 2 + j) * 16 + n16;
            float v[4] = {acc[tm][j][0] + bb.x, acc[tm][j][1] + bb.y,
                          acc[tm][j][2] + bb.z, acc[tm][j][3] + bb.w};
            e -= 0.5f * (v[0]*v[0] + v[1]*v[1] + v[2]*v[2] + v[3]*v[3]);
            if (o0 < HID) {                       // Q: scaled by SCALE*log2e
                const int h = o0 >> 5, dh0 = o0 & 31;
                const float qs = SCALE * LOG2E;
                short4 pk = {f2bf(v[0]*qs), f2bf(v[1]*qs),
                             f2bf(v[2]*qs), f2bf(v[3]*qs)};
                *(short4*)(Qb + ((size_t)(b * NH + h) * HW + s) * DH + dh0) = pk;
            } else if (o0 < 2 * HID) {            // K: sigma-permuted rows + K^T copy
                const int c = o0 - HID, h = c >> 5, dh0 = c & 31;
                const int g = s & 31;
                const int sp = (s & ~31) | ((g & 4) << 2) | ((g >> 3) << 2) | (g & 3);
                short4 pk = {f2bf(v[0]), f2bf(v[1]), f2bf(v[2]), f2bf(v[3])};
                *(short4*)(Kb + ((size_t)(b * NH + h) * HW + sp) * DH + dh0) = pk;
                #pragma unroll
                for (int r = 0; r < 4; ++r)
                    Kt[((size_t)(b * NH + h) * DH + dh0 + r) * HW + s] = f2bf(v[r]);
            } else {                              // V: [bh][dh][s]
                const int c = o0 - 2 * HID, h = c >> 5, dh0 = c & 31;
                #pragma unroll
                for (int r = 0; r < 4; ++r)
                    Vb[((size_t)(b * NH + h) * DH + dh0 + r) * HW + s] = f2bf(v[r]);
            }
        }
    }

    #pragma unroll
    for (int off = 32; off > 0; off >>= 1) e += __shfl_down(e, off);
    if (lane == 0) red[w] = e;
    __syncthreads();
    if (t == 0) atomicAdd(E, red[0] + red[1] + red[2] + red[3]);
}

// ---------------------------------------------------------------------------
// Flash attention r11 = r10 flash (split-K NSPLIT=4, swapped-operand, MFMA
// softmax stats, qg=2, ring-2 minimal 2-phase) + XCD-AWARE BLOCK SWIZZLE:
// flat id -> (xcd = flat&7, j = flat>>3, g = xcd + 8*(j/18), m = j%18);
// group g = (bh,kh) pair, member m = q-block. All 18 q-blocks sharing one
// (bh,kh) K/V/Kt range (108 KB) land on ONE XCD -> L2-resident reuse
// (16 groups x 108 KB = 1.7 MB per 4 MB XCD-L2). Bijective: 2304 = 8*16*18.
// ---------------------------------------------------------------------------
__global__ __launch_bounds__(256)
void flashsplit(const short* __restrict__ Qb, const short* __restrict__ Kb,
                const short* __restrict__ Kt, const short* __restrict__ Vb,
                short* __restrict__ Oh, float* __restrict__ lsP,
                float* __restrict__ tsP)
{
    __shared__ __align__(16) char smem[2 * 12288];
    // buffer p at p*12288; chunk ca at +ca*6144:
    //   [K keys0-15 |1KB| K keys16-31 |1KB| V dh0-15 | V dh16-31 | Kt dh0-15 | Kt dh16-31]

    constexpr int ITERS = HW / (NSPLIT * 64);   // 9
    // XCD-aware swizzle of the (18, 32, 4) grid
    const int flat = blockIdx.x + 18 * (blockIdx.y + 32 * blockIdx.z);
    const int xcd  = flat & 7, j = flat >> 3;
    const int g    = xcd + 8 * (j / 18);        // group 0..127 = (bh,kh)
    const int m    = j % 18;                    // q-block 0..17
    const int bh   = g & 31;
    const int kh   = g >> 5;                    // key quarter: 0..3
    const int w    = threadIdx.x >> 6;
    const int lane = threadIdx.x & 63;
    const int n16  = lane & 15, quad = lane >> 4;
    const int qb   = m * 128 + w * 32;
    const int key0 = kh * ITERS * 64;           // this block's key range start

    bf16x8 aq[2];
    #pragma unroll
    for (int qg = 0; qg < 2; ++qg)
        aq[qg] = *(const bf16x8*)(Qb + ((size_t)bh * HW + qb + qg * 16 + n16) * DH + quad * 8);
    SB();

    // DMA roles (3 gld16/wave/iter): w0: K ca0 (2) + Kt ca0 u0; w1: K ca1 (2)
    // + Kt ca0 u1; w2: V ca0 (2) + Kt ca1 u0; w3: V ca1 (2) + Kt ca1 u1.
    const int rL = lane >> 2, cL = (lane & 3) ^ (rL & 3);
    const char* Kglb  = (const char*)(Kb + (size_t)bh * HW * DH);
    const char* Vglb  = (const char*)(Vb + (size_t)bh * DH * HW);
    const char* Ktglb = (const char*)(Kt + (size_t)bh * DH * HW);
    const int pca  = w & 1;                     // primary chunk
    const int ktca = w >> 1;                    // Kt chunk
    const int ktu  = w & 1;                     // Kt dh-half

    auto stage = [&](int it, int pbuf) {
        char* buf = smem + pbuf * 12288;
        const int k64 = key0 + it * 64;
        if (w < 2) {                            // K tile, chunk pca (32 keys)
            const char* kg = Kglb + (size_t)(k64 + pca * 32 + rL) * 64 + cL * 16;
            gld16(kg,        buf + pca * 6144 + 0);
            gld16(kg + 1024, buf + pca * 6144 + 1024);   // +16 keys
        } else {                                // V tile, chunk pca
            const char* vg = Vglb + (size_t)rL * HW2 + (size_t)(k64 + pca * 32) * 2 + cL * 16;
            gld16(vg,             buf + pca * 6144 + 2048);
            gld16(vg + 16 * HW2,  buf + pca * 6144 + 3072);  // dh 16-31
        }
        const char* kt = Ktglb + (size_t)(ktu * 16 + rL) * HW2
                       + (size_t)(k64 + ktca * 32) * 2 + cL * 16;
        gld16(kt, buf + ktca * 6144 + 4096 + ktu * 1024);
    };

    stage(0, 0);
    SB();

    f32x4 acc[2][2] = {};                     // [qg][dh-half]: O^T[q=n16][dh]
    f32x4 lsacc[2] = {};                      // ones-MFMA: all rows = ls_q
    f32x4 tsacc[2][2] = {};                   // [qg][dh-half]: (P.K^T)[dh][q]
    const int swz = (quad ^ (n16 & 3)) * 8;   // frag-read XOR swizzle (shorts)
    const bf16x8 ones = {0x3F80, 0x3F80, 0x3F80, 0x3F80,
                         0x3F80, 0x3F80, 0x3F80, 0x3F80};   // bf16 1.0 x8

    for (int it = 0; it < ITERS; ++it) {
        const int p = it & 1;
        asm volatile("s_waitcnt vmcnt(0)" ::: "memory");   // stage(it) landed (aged 1 phase)
        __builtin_amdgcn_s_barrier();
        SB();
        if (it + 1 < ITERS) stage(it + 1, p ^ 1);          // overwrites buf read at it-1

        const char* buf = smem + p * 12288;
        #pragma unroll
        for (int ca = 0; ca < 2; ++ca) {
            const short* cb = (const short*)(buf + ca * 6144);

            const bf16x8 bk0  = *(const bf16x8*)(cb +        n16 * 32 + swz);  // keypos 0-15
            const bf16x8 bk1  = *(const bf16x8*)(cb + 512  + n16 * 32 + swz);  // keypos 16-31
            const bf16x8 bv0  = *(const bf16x8*)(cb + 1024 + n16 * 32 + swz);  // V dh 0-15
            const bf16x8 bv1  = *(const bf16x8*)(cb + 1536 + n16 * 32 + swz);  // V dh 16-31
            const bf16x8 bkt0 = *(const bf16x8*)(cb + 2048 + n16 * 32 + swz);  // Kt dh 0-15
            const bf16x8 bkt1 = *(const bf16x8*)(cb + 2560 + n16 * 32 + swz);  // Kt dh 16-31

            #pragma unroll
            for (int qg = 0; qg < 2; ++qg) {
                f32x4 z = {};
                // swapped: C row = key position, col = query n16
                const f32x4 s0 = __builtin_amdgcn_mfma_f32_16x16x32_bf16(bk0, aq[qg], z, 0, 0, 0);
                const f32x4 s1 = __builtin_amdgcn_mfma_f32_16x16x32_bf16(bk1, aq[qg], z, 0, 0, 0);
                float e0[4], e1[4];
                #pragma unroll
                for (int r = 0; r < 4; ++r) {
                    e0[r] = __builtin_amdgcn_exp2f(s0[r]);   // key quad*8+r
                    e1[r] = __builtin_amdgcn_exp2f(s1[r]);   // key quad*8+4+r
                }
                union { bf16x8 v; unsigned u[4]; } pa;
                pa.u[0] = pk2bf(e0[0], e0[1]);
                pa.u[1] = pk2bf(e0[2], e0[3]);
                pa.u[2] = pk2bf(e1[0], e1[1]);
                pa.u[3] = pk2bf(e1[2], e1[3]);
                // swapped PV: C row = dh part, col = query n16
                acc[qg][0]   = __builtin_amdgcn_mfma_f32_16x16x32_bf16(bv0,  pa.v, acc[qg][0], 0, 0, 0);
                acc[qg][1]   = __builtin_amdgcn_mfma_f32_16x16x32_bf16(bv1,  pa.v, acc[qg][1], 0, 0, 0);
                lsacc[qg]    = __builtin_amdgcn_mfma_f32_16x16x32_bf16(ones, pa.v, lsacc[qg], 0, 0, 0);
                tsacc[qg][0] = __builtin_amdgcn_mfma_f32_16x16x32_bf16(bkt0, pa.v, tsacc[qg][0], 0, 0, 0);
                tsacc[qg][1] = __builtin_amdgcn_mfma_f32_16x16x32_bf16(bkt1, pa.v, tsacc[qg][1], 0, 0, 0);
            }
        }
    }

    const int bb = bh >> 2, h = bh & 3;
    short* dst = Oh + (size_t)kh * OSZ;
    #pragma unroll
    for (int qg = 0; qg < 2; ++qg) {
        const int q = qb + qg * 16 + n16;
        const float L = lsacc[qg][0];           // all rows equal
        // ts = q_scaled . (P.K^T): dot 8 local dh, then quad-reduce
        const short4 qa = *(const short4*)(Qb + ((size_t)bh * HW + q) * DH + quad * 4);
        const short4 qc = *(const short4*)(Qb + ((size_t)bh * HW + q) * DH + 16 + quad * 4);
        float ts = bf2f(qa.x) * tsacc[qg][0][0] + bf2f(qa.y) * tsacc[qg][0][1]
                 + bf2f(qa.z) * tsacc[qg][0][2] + bf2f(qa.w) * tsacc[qg][0][3]
                 + bf2f(qc.x) * tsacc[qg][1][0] + bf2f(qc.y) * tsacc[qg][1][1]
                 + bf2f(qc.z) * tsacc[qg][1][2] + bf2f(qc.w) * tsacc[qg][1][3];
        ts += __shfl_xor(ts, 16);
        ts += __shfl_xor(ts, 32);

        const float invl = 1.f / L;
        short* ap = dst + ((size_t)bb * HW + q) * HID + h * 32;
        short4 pk0 = {f2bf(acc[qg][0][0] * invl), f2bf(acc[qg][0][1] * invl),
                      f2bf(acc[qg][0][2] * invl), f2bf(acc[qg][0][3] * invl)};
        short4 pk1 = {f2bf(acc[qg][1][0] * invl), f2bf(acc[qg][1][1] * invl),
                      f2bf(acc[qg][1][2] * invl), f2bf(acc[qg][1][3] * invl)};
        *(short4*)(ap + quad * 4)      = pk0;   // dh quad*4 .. +3
        *(short4*)(ap + 16 + quad * 4) = pk1;   // dh 16+quad*4 .. +3
        if (quad == 0) {
            const size_t li = (size_t)(kh * 32 + bh) * HW + q;
            lsP[li] = L;
            tsP[li] = ts;
        }
    }
}

// ---------------------------------------------------------------------------
// Output conv with FUSED split-K combine (unchanged): B-tile =
// sum_kh w_kh*Oh[kh] built in registers, ds_write'n to LDS; K-chunk == head.
// bm==0 blocks fold in the softmax-Lagrangian energy. Ticketed final E store.
// ---------------------------------------------------------------------------
__global__ __launch_bounds__(256, 2)
void conv_out(const short* __restrict__ A, const short* __restrict__ Oh,
              const float* __restrict__ lsP, const float* __restrict__ tsP,
              const float* __restrict__ bias, float* __restrict__ out0,
              float* __restrict__ E, int* __restrict__ ticket, int nblocks,
              float* __restrict__ edst)
{
    constexpr int KD = HID;                     // 128
    constexpr int NI = KD / 32;                 // 4 chunks == 4 heads
    const int b  = blockIdx.z;
    const int bm = blockIdx.y * 64;
    const int bn = blockIdx.x * 128;
    const int t  = threadIdx.x;
    const int w  = t >> 6, lane = t & 63;
    const int n16 = lane & 15, quad = lane >> 4;

    __shared__ __align__(16) char csm[24576];   // 2 x (A 4KB | B 8KB)
    __shared__ float red[4];

    const int rL = lane >> 2, cswz = (lane & 3) ^ (rL & 3);
    const char* agl = (const char*)(A + (size_t)(bm + rL) * KD + cswz * 8);

    auto issueA = [&](int kc, int pbuf) {       // 4 x 1KB, waves 0-1
        char* base = csm + pbuf * 12288;
        if (w == 0) {
            gld16(agl + (size_t)(0 * 16 * KD + kc) * 2, base + 0 * 1024);
            gld16(agl + (size_t)(1 * 16 * KD + kc) * 2, base + 1 * 1024);
        } else if (w == 1) {
            gld16(agl + (size_t)(2 * 16 * KD + kc) * 2, base + 2 * 1024);
            gld16(agl + (size_t)(3 * 16 * KD + kc) * 2, base + 3 * 1024);
        }
    };

    // fused-combine B loader: 2 deposits/wave (16-pixel blocks w*2, w*2+1)
    auto loadB = [&](int ki, bf16x8 pk[2]) {
        const int kc = ki * 32;
        const int bh = b * NH + ki;             // chunk == head
        #pragma unroll
        for (int d = 0; d < 2; ++d) {
            const int blk = w * 2 + d;
            const int q = bn + blk * 16 + rL;
            float Ls[NSPLIT], sum = 0.f;
            #pragma unroll
            for (int kh = 0; kh < NSPLIT; ++kh) {
                Ls[kh] = lsP[(size_t)(kh * 32 + bh) * HW + q];
                sum += Ls[kh];
            }
            const float inv = 1.f / sum;
            float vv[8] = {};
            #pragma unroll
            for (int kh = 0; kh < NSPLIT; ++kh) {
                const float wk = Ls[kh] * inv;
                const bf16x8 o = *(const bf16x8*)(Oh + (size_t)kh * OSZ
                                    + ((size_t)b * HW + q) * HID + kc + cswz * 8);
                #pragma unroll
                for (int j = 0; j < 8; ++j) vv[j] += wk * bf2f(o[j]);
            }
            union { bf16x8 v; unsigned u[4]; } c;
            #pragma unroll
            for (int i = 0; i < 4; ++i) c.u[i] = pk2bf(vv[2*i], vv[2*i+1]);
            pk[d] = c.v;
        }
    };
    auto writeB = [&](const bf16x8 pk[2], int pbuf) {
        char* base = csm + pbuf * 12288 + 4096;
        #pragma unroll
        for (int d = 0; d < 2; ++d) {
            const int blk = w * 2 + d;
            *(bf16x8*)(base + blk * 1024 + rL * 64 + (lane & 3) * 16) = pk[d];
        }
    };

    f32x4 acc[4][2] = {};
    const int rsw = (quad ^ (n16 & 3)) * 16;    // frag-read swizzle (bytes)

    bf16x8 bpk[2];
    loadB(0, bpk);
    issueA(0, 0);
    writeB(bpk, 0);
    for (int ki = 0; ki < NI; ++ki) {
        const int p = ki & 1;
        __syncthreads();                        // chunk ki landed (A DMA + B writes)
        if (ki + 1 < NI) { loadB(ki + 1, bpk); issueA((ki + 1) * 32, p ^ 1); }

        const char* Ap = csm + p * 12288;
        const char* Bp = Ap + 4096;
        bf16x8 am[4], bq[2];
        #pragma unroll
        for (int tm = 0; tm < 4; ++tm)
            am[tm] = *(const bf16x8*)(Ap + tm * 1024 + n16 * 64 + rsw);
        #pragma unroll
        for (int j = 0; j < 2; ++j)
            bq[j] = *(const bf16x8*)(Bp + (w * 2 + j) * 1024 + n16 * 64 + rsw);
        #pragma unroll
        for (int tm = 0; tm < 4; ++tm)
            #pragma unroll
            for (int j = 0; j < 2; ++j)
                acc[tm][j] = __builtin_amdgcn_mfma_f32_16x16x32_bf16(am[tm], bq[j], acc[tm][j], 0, 0, 0);

        if (ki + 1 < NI) writeB(bpk, p ^ 1);    // after this chunk's frag reads
    }

    float e = 0.f;
    #pragma unroll
    for (int tm = 0; tm < 4; ++tm) {
        const int o0 = bm + tm * 16 + quad * 4;
        const float4 bb = *(const float4*)(bias + o0);
        #pragma unroll
        for (int j = 0; j < 2; ++j) {
            const int s = bn + (w * 2 + j) * 16 + n16;
            float v[4] = {acc[tm][j][0] + bb.x, acc[tm][j][1] + bb.y,
                          acc[tm][j][2] + bb.z, acc[tm][j][3] + bb.w};
            e -= 0.5f * (v[0]*v[0] + v[1]*v[1] + v[2]*v[2] + v[3]*v[3]);
            #pragma unroll
            for (int r = 0; r < 4; ++r)
                out0[((size_t)b * NC + o0 + r) * HW + s] = v[r];
        }
    }

    if (blockIdx.y == 0) {                      // attention energy, once per (b,q,h)
        const int q = bn + (t & 127);
        #pragma unroll
        for (int jj = 0; jj < 2; ++jj) {
            const int h = (t >> 7) * 2 + jj;
            const int bh = b * NH + h;
            float L = 0.f, T = 0.f;
            #pragma unroll
            for (int kh = 0; kh < NSPLIT; ++kh) {
                L += lsP[(size_t)(kh * 32 + bh) * HW + q];
                T += tsP[(size_t)(kh * 32 + bh) * HW + q];
            }
            e += (LN2 * T) / L - __logf(L);
        }
    }

    #pragma unroll
    for (int off = 32; off > 0; off >>= 1) e += __shfl_down(e, off);
    if (lane == 0) red[w] = e;
    __syncthreads();
    if (t == 0) {
        atomicAdd(E, red[0] + red[1] + red[2] + red[3]);
        __threadfence();
        const int prev = atomicAdd(ticket, 1);
        if (prev == nblocks - 1) {
            __threadfence();
            edst[0] = atomicAdd(E, 0.f);
        }
    }
}

// ---------------------------------------------------------------------------
extern "C" void kernel_launch(void* const* d_in, const int* in_sizes, int n_in,
                              void* d_out, int out_size, void* d_ws, size_t ws_size,
                              hipStream_t stream) {
    const float* x     = (const float*)d_in[0];
    const float* w_qkv = (const float*)d_in[1];
    const float* b_qkv = (const float*)d_in[2];
    const float* w_out = (const float*)d_in[3];
    const float* b_out = (const float*)d_in[4];
    float* out = (float*)d_out;

    float* wsf    = (float*)d_ws;
    float* E      = wsf;                               // [0] energy accumulator
    int*   ticket = (int*)d_ws + 1;                    // [1] conv_out ticket
    short* Xt   = (short*)(wsf + 16);                  // bf16 [b][s][c]
    short* Wq   = Xt + (size_t)NB * HW * NC;           // bf16 [384][256]
    short* Wo   = Wq + 384 * 256;                      // bf16 [256][128]
    short* Qb   = Wo + 256 * 128;                      // bf16 [bh][s][dh] (xSCALE*log2e)
    short* Kb   = Qb + (size_t)NB * NH * HW * DH;      // bf16 [bh][s'][dh], sigma-permuted
    short* Ktb  = Kb + (size_t)NB * NH * HW * DH;      // bf16 [bh][dh][s] (K^T)
    short* Vb   = Ktb + (size_t)NB * NH * HW * DH;     // bf16 [bh][dh][s]
    short* Oh   = Vb + (size_t)NB * NH * HW * DH;      // bf16 [NSPLIT][b][s][hid]
    float* lsP  = (float*)(Oh + NSPLIT * OSZ);         // f32 [NSPLIT][32][HW]
    float* tsP  = lsP + NSPLIT * 32 * HW;              // f32 [NSPLIT][32][HW]

    prep<<<dim3(HW / 64, NC / 64, NB + 1), 256, 0, stream>>>(
        x, w_qkv, w_out, Xt, Wq, Wo, wsf);
    conv_qkv<<<dim3(18, 6, NB), 256, 0, stream>>>(
        Wq, Xt, b_qkv, Qb, Kb, Ktb, Vb, E);
    flashsplit<<<dim3(HW / 128, NB * NH, NSPLIT), 256, 0, stream>>>(
        Qb, Kb, Ktb, Vb, Oh, lsP, tsP);
    conv_out<<<dim3(18, 4, NB), 256, 0, stream>>>(
        Wo, Oh, lsP, tsP, b_out, out, E, ticket, 18 * 4 * NB,
        out + (size_t)NB * NC * HW);
}

// Round 12
// 181.794 us; speedup vs baseline: 1.0657x; 1.0657x over previous
//
#include <hip/hip_runtime.h>
#include <hip/hip_bf16.h>

#define HW 2304          // 48*48
#define HW2 4608         // HW * sizeof(bf16)
#define NB 8             // batch
#define NC 256           // input channels
#define HID 128          // heads*dim_head
#define DH 32            // dim_head
#define NH 4             // heads
#define SCALE 0.17677669529663687f   // 1/sqrt(32)
#define LOG2E 1.4426950408889634f
#define LN2   0.6931471805599453f

#define NSPLIT 4         // flash split-K factor
#define OSZ ((size_t)NB * HW * HID)   // one O-partial

using bf16x8 = __attribute__((ext_vector_type(8))) short;
using f32x4  = __attribute__((ext_vector_type(4))) float;

__device__ __forceinline__ short f2bf(float f) {   // RNE float->bf16
    unsigned u = __float_as_uint(f);
    u += 0x7FFF + ((u >> 16) & 1);
    return (short)(u >> 16);
}
__device__ __forceinline__ float bf2f(short s) {
    return __uint_as_float(((unsigned)(unsigned short)s) << 16);
}
__device__ __forceinline__ unsigned pk2bf(float a, float b) {  // pack 2 bf16 (RNE)
    union { __hip_bfloat162 h; unsigned u; } cv;
    cv.h = __float22bfloat162_rn(float2{a, b});
    return cv.u;
}
__device__ __forceinline__ void gld16(const void* g, void* l) {  // 16B global->LDS DMA
    __builtin_amdgcn_global_load_lds(
        (const __attribute__((address_space(1))) unsigned*)g,
        (__attribute__((address_space(3))) unsigned*)l, 16, 0, 0);
}
#define SB() __builtin_amdgcn_sched_barrier(0)

// ---------------------------------------------------------------------------
// Fused pre-pass, VECTORIZED (r10). z<8: x [b][256][2304] fp32 ->
// Xt [b][2304][256] bf16 via 64x64 tiles: float4 coalesced reads (16B/lane),
// bf16 LDS tile [64 s][72 c], bf16x8 aligned stores (16B/lane).
// z==8: weight fp32->bf16 conversion (sweep loop) + zero E/ticket words.
// ---------------------------------------------------------------------------
__global__ __launch_bounds__(256)
void prep(const float* __restrict__ x, const float* __restrict__ wq,
          const float* __restrict__ wo, short* __restrict__ Xt,
          short* __restrict__ Wq, short* __restrict__ Wo, float* __restrict__ wsz)
{
    if (blockIdx.z == 8) {
        const int bid = blockIdx.x + 36 * blockIdx.y;   // 0..143
        if (bid == 0 && threadIdx.x == 0) { wsz[0] = 0.f; ((int*)wsz)[1] = 0; }
        for (int i = bid * 256 + threadIdx.x; i < 384 * 256; i += 144 * 256) {
            Wq[i] = f2bf(wq[i]);
            if (i < 256 * 128) Wo[i] = f2bf(wo[i]);
        }
        return;
    }
    __shared__ short Tb[64][72];                 // bf16 [s][c], pad 72
    const int b = blockIdx.z, c0 = blockIdx.y * 64, s0 = blockIdx.x * 64;
    const int ts4 = (threadIdx.x & 15) * 4;      // 4 s per thread
    const int cc0 = threadIdx.x >> 4;            // 16 c rows per pass
    #pragma unroll
    for (int pp = 0; pp < 4; ++pp) {
        const int cc = cc0 + pp * 16;
        const float4 v = *(const float4*)(
            x + ((size_t)b * NC + c0 + cc) * HW + s0 + ts4);
        Tb[ts4 + 0][cc] = f2bf(v.x);
        Tb[ts4 + 1][cc] = f2bf(v.y);
        Tb[ts4 + 2][cc] = f2bf(v.z);
        Tb[ts4 + 3][cc] = f2bf(v.w);
    }
    __syncthreads();
    const int ss = threadIdx.x >> 2;             // 64 s
    const int c8 = (threadIdx.x & 3) * 8;        // c octet
    #pragma unroll
    for (int pp = 0; pp < 2; ++pp) {
        const int cc = c8 + pp * 32;
        const bf16x8 v = *(const bf16x8*)&Tb[ss][cc];
        *(bf16x8*)(Xt + ((size_t)b * HW + s0 + ss) * NC + c0 + cc) = v;
    }
}

// ---------------------------------------------------------------------------
// QKV MFMA 1x1-conv GEMM (r11 BK=64 schedule) + r12 XCD SWIZZLE: the 6
// bm-blocks sharing one B-panel (128 px x 256 ch of Xt, 64 KB) colocate on
// one XCD -> B fetched once per XCD instead of ~4x across XCDs.
// 864 = 8 xcd x 18 groups x 6 members; per-XCD B footprint 1.15 MB (< 4MB L2).
// Epilogue: Q(xSCALE*LOG2E); K sigma-permuted + Kt [bh][dh][s]; V [bh][dh][s].
// ---------------------------------------------------------------------------
__global__ __launch_bounds__(256, 2)
void conv_qkv(const short* __restrict__ A, const short* __restrict__ Bt,
              const float* __restrict__ bias,
              short* __restrict__ Qb, short* __restrict__ Kb,
              short* __restrict__ Kt, short* __restrict__ Vb,
              float* __restrict__ E)
{
    constexpr int KD = NC;
    constexpr int NI = KD / 64;                 // 4 chunks of 64-K
    // XCD swizzle: group g = (bn,b) B-panel, member m = bm
    const int flat = blockIdx.x + 18 * (blockIdx.y + 6 * blockIdx.z);
    const int xcd  = flat & 7, j = flat >> 3;   // j: 0..107
    const int g    = xcd + 8 * (j / 6);         // 0..143
    const int b    = g / 18;
    const int bn   = (g % 18) * 128;
    const int bm   = (j % 6) * 64;
    const int t  = threadIdx.x;
    const int w  = t >> 6, lane = t & 63;
    const int n16 = lane & 15, quad = lane >> 4;

    __shared__ __align__(16) char csm[2 * 24576];   // ring-2 x 64-K chunk (24KB)
    __shared__ float red[4];

    const int rL = lane >> 2, cswz = (lane & 3) ^ (rL & 3);
    const char* agl = (const char*)(A  + (size_t)(bm + rL) * KD + cswz * 8);
    const char* bgl = (const char*)(Bt + ((size_t)b * HW + bn + rL) * KD + cswz * 8);

    auto issue32 = [&](int kc, char* base) {    // one 32-K unit, 3 gld16/wave
        if (w == 0) {
            gld16(agl + (size_t)(0 * 16 * KD + kc) * 2, base + 0 * 1024);
            gld16(agl + (size_t)(1 * 16 * KD + kc) * 2, base + 1 * 1024);
            gld16(bgl + (size_t)(0 * 16 * KD + kc) * 2, base + 4096 + 0 * 1024);
        } else if (w == 1) {
            gld16(agl + (size_t)(2 * 16 * KD + kc) * 2, base + 2 * 1024);
            gld16(agl + (size_t)(3 * 16 * KD + kc) * 2, base + 3 * 1024);
            gld16(bgl + (size_t)(1 * 16 * KD + kc) * 2, base + 4096 + 1 * 1024);
        } else if (w == 2) {
            gld16(bgl + (size_t)(2 * 16 * KD + kc) * 2, base + 4096 + 2 * 1024);
            gld16(bgl + (size_t)(3 * 16 * KD + kc) * 2, base + 4096 + 3 * 1024);
            gld16(bgl + (size_t)(4 * 16 * KD + kc) * 2, base + 4096 + 4 * 1024);
        } else {
            gld16(bgl + (size_t)(5 * 16 * KD + kc) * 2, base + 4096 + 5 * 1024);
            gld16(bgl + (size_t)(6 * 16 * KD + kc) * 2, base + 4096 + 6 * 1024);
            gld16(bgl + (size_t)(7 * 16 * KD + kc) * 2, base + 4096 + 7 * 1024);
        }
    };
    auto stage = [&](int kc, int pbuf) {        // 64-K chunk, 6 gld16/wave
        issue32(kc,      csm + pbuf * 24576);
        issue32(kc + 32, csm + pbuf * 24576 + 12288);
    };

    f32x4 acc[4][2] = {};
    const int rsw = (quad ^ (n16 & 3)) * 16;    // frag-read swizzle (bytes)

    stage(0, 0); SB();
    for (int ki = 0; ki < NI; ++ki) {
        const int p = ki & 1;
        asm volatile("s_waitcnt vmcnt(0)" ::: "memory");   // stage(ki) landed (aged 1 phase)
        __builtin_amdgcn_s_barrier();
        SB();
        if (ki + 1 < NI) stage((ki + 1) * 64, p ^ 1);      // overwrites buf read at ki-1

        #pragma unroll
        for (int su = 0; su < 2; ++su) {
            const char* Ap = csm + p * 24576 + su * 12288;
            const char* Bp = Ap + 4096;
            bf16x8 am[4], bq[2];
            #pragma unroll
            for (int tm = 0; tm < 4; ++tm)
                am[tm] = *(const bf16x8*)(Ap + tm * 1024 + n16 * 64 + rsw);
            #pragma unroll
            for (int j2 = 0; j2 < 2; ++j2)
                bq[j2] = *(const bf16x8*)(Bp + (w * 2 + j2) * 1024 + n16 * 64 + rsw);
            #pragma unroll
            for (int tm = 0; tm < 4; ++tm)
                #pragma unroll
                for (int j2 = 0; j2 < 2; ++j2)
                    acc[tm][j2] = __builtin_amdgcn_mfma_f32_16x16x32_bf16(am[tm], bq[j2], acc[tm][j2], 0, 0, 0);
        }
    }

    float e = 0.f;
    #pragma unroll
    for (int tm = 0; tm < 4; ++tm) {
        const int o0 = bm + tm * 16 + quad * 4;
        const float4 bb = *(const float4*)(bias + o0);
        #pragma unroll
        for (int j2 = 0; j2 < 2; ++j2) {
            const int s = bn + (w * 2 + j2) * 16 + n16;
            float v[4] = {acc[tm][j2][0] + bb.x, acc[tm][j2][1] + bb.y,
                          acc[tm][j2][2] + bb.z, acc[tm][j2][3] + bb.w};
            e -= 0.5f * (v[0]*v[0] + v[1]*v[1] + v[2]*v[2] + v[3]*v[3]);
            if (o0 < HID) {                       // Q: scaled by SCALE*log2e
                const int h = o0 >> 5, dh0 = o0 & 31;
                const float qs = SCALE * LOG2E;
                short4 pk = {f2bf(v[0]*qs), f2bf(v[1]*qs),
                             f2bf(v[2]*qs), f2bf(v[3]*qs)};
                *(short4*)(Qb + ((size_t)(b * NH + h) * HW + s) * DH + dh0) = pk;
            } else if (o0 < 2 * HID) {            // K: sigma-permuted rows + K^T copy
                const int c = o0 - HID, h = c >> 5, dh0 = c & 31;
                const int gg = s & 31;
                const int sp = (s & ~31) | ((gg & 4) << 2) | ((gg >> 3) << 2) | (gg & 3);
                short4 pk = {f2bf(v[0]), f2bf(v[1]), f2bf(v[2]), f2bf(v[3])};
                *(short4*)(Kb + ((size_t)(b * NH + h) * HW + sp) * DH + dh0) = pk;
                #pragma unroll
                for (int r = 0; r < 4; ++r)
                    Kt[((size_t)(b * NH + h) * DH + dh0 + r) * HW + s] = f2bf(v[r]);
            } else {                              // V: [bh][dh][s]
                const int c = o0 - 2 * HID, h = c >> 5, dh0 = c & 31;
                #pragma unroll
                for (int r = 0; r < 4; ++r)
                    Vb[((size_t)(b * NH + h) * DH + dh0 + r) * HW + s] = f2bf(v[r]);
            }
        }
    }

    #pragma unroll
    for (int off = 32; off > 0; off >>= 1) e += __shfl_down(e, off);
    if (lane == 0) red[w] = e;
    __syncthreads();
    if (t == 0) atomicAdd(E, red[0] + red[1] + red[2] + red[3]);
}

// ---------------------------------------------------------------------------
// Flash attention (r11, unchanged): split-K NSPLIT=4, swapped-operand MFMAs,
// MFMA softmax stats, qg=2, ring-2 minimal 2-phase, XCD swizzle (groups of 18
// q-blocks sharing one (bh,kh) K/V/Kt range on one XCD).
// ---------------------------------------------------------------------------
__global__ __launch_bounds__(256)
void flashsplit(const short* __restrict__ Qb, const short* __restrict__ Kb,
                const short* __restrict__ Kt, const short* __restrict__ Vb,
                short* __restrict__ Oh, float* __restrict__ lsP,
                float* __restrict__ tsP)
{
    __shared__ __align__(16) char smem[2 * 12288];
    // buffer p at p*12288; chunk ca at +ca*6144:
    //   [K keys0-15 |1KB| K keys16-31 |1KB| V dh0-15 | V dh16-31 | Kt dh0-15 | Kt dh16-31]

    constexpr int ITERS = HW / (NSPLIT * 64);   // 9
    // XCD-aware swizzle of the (18, 32, 4) grid
    const int flat = blockIdx.x + 18 * (blockIdx.y + 32 * blockIdx.z);
    const int xcd  = flat & 7, j = flat >> 3;
    const int g    = xcd + 8 * (j / 18);        // group 0..127 = (bh,kh)
    const int m    = j % 18;                    // q-block 0..17
    const int bh   = g & 31;
    const int kh   = g >> 5;                    // key quarter: 0..3
    const int w    = threadIdx.x >> 6;
    const int lane = threadIdx.x & 63;
    const int n16  = lane & 15, quad = lane >> 4;
    const int qb   = m * 128 + w * 32;
    const int key0 = kh * ITERS * 64;           // this block's key range start

    bf16x8 aq[2];
    #pragma unroll
    for (int qg = 0; qg < 2; ++qg)
        aq[qg] = *(const bf16x8*)(Qb + ((size_t)bh * HW + qb + qg * 16 + n16) * DH + quad * 8);
    SB();

    // DMA roles (3 gld16/wave/iter): w0: K ca0 (2) + Kt ca0 u0; w1: K ca1 (2)
    // + Kt ca0 u1; w2: V ca0 (2) + Kt ca1 u0; w3: V ca1 (2) + Kt ca1 u1.
    const int rL = lane >> 2, cL = (lane & 3) ^ (rL & 3);
    const char* Kglb  = (const char*)(Kb + (size_t)bh * HW * DH);
    const char* Vglb  = (const char*)(Vb + (size_t)bh * DH * HW);
    const char* Ktglb = (const char*)(Kt + (size_t)bh * DH * HW);
    const int pca  = w & 1;                     // primary chunk
    const int ktca = w >> 1;                    // Kt chunk
    const int ktu  = w & 1;                     // Kt dh-half

    auto stage = [&](int it, int pbuf) {
        char* buf = smem + pbuf * 12288;
        const int k64 = key0 + it * 64;
        if (w < 2) {                            // K tile, chunk pca (32 keys)
            const char* kg = Kglb + (size_t)(k64 + pca * 32 + rL) * 64 + cL * 16;
            gld16(kg,        buf + pca * 6144 + 0);
            gld16(kg + 1024, buf + pca * 6144 + 1024);   // +16 keys
        } else {                                // V tile, chunk pca
            const char* vg = Vglb + (size_t)rL * HW2 + (size_t)(k64 + pca * 32) * 2 + cL * 16;
            gld16(vg,             buf + pca * 6144 + 2048);
            gld16(vg + 16 * HW2,  buf + pca * 6144 + 3072);  // dh 16-31
        }
        const char* kt = Ktglb + (size_t)(ktu * 16 + rL) * HW2
                       + (size_t)(k64 + ktca * 32) * 2 + cL * 16;
        gld16(kt, buf + ktca * 6144 + 4096 + ktu * 1024);
    };

    stage(0, 0);
    SB();

    f32x4 acc[2][2] = {};                     // [qg][dh-half]: O^T[q=n16][dh]
    f32x4 lsacc[2] = {};                      // ones-MFMA: all rows = ls_q
    f32x4 tsacc[2][2] = {};                   // [qg][dh-half]: (P.K^T)[dh][q]
    const int swz = (quad ^ (n16 & 3)) * 8;   // frag-read XOR swizzle (shorts)
    const bf16x8 ones = {0x3F80, 0x3F80, 0x3F80, 0x3F80,
                         0x3F80, 0x3F80, 0x3F80, 0x3F80};   // bf16 1.0 x8

    for (int it = 0; it < ITERS; ++it) {
        const int p = it & 1;
        asm volatile("s_waitcnt vmcnt(0)" ::: "memory");   // stage(it) landed (aged 1 phase)
        __builtin_amdgcn_s_barrier();
        SB();
        if (it + 1 < ITERS) stage(it + 1, p ^ 1);          // overwrites buf read at it-1

        const char* buf = smem + p * 12288;
        #pragma unroll
        for (int ca = 0; ca < 2; ++ca) {
            const short* cb = (const short*)(buf + ca * 6144);

            const bf16x8 bk0  = *(const bf16x8*)(cb +        n16 * 32 + swz);  // keypos 0-15
            const bf16x8 bk1  = *(const bf16x8*)(cb + 512  + n16 * 32 + swz);  // keypos 16-31
            const bf16x8 bv0  = *(const bf16x8*)(cb + 1024 + n16 * 32 + swz);  // V dh 0-15
            const bf16x8 bv1  = *(const bf16x8*)(cb + 1536 + n16 * 32 + swz);  // V dh 16-31
            const bf16x8 bkt0 = *(const bf16x8*)(cb + 2048 + n16 * 32 + swz);  // Kt dh 0-15
            const bf16x8 bkt1 = *(const bf16x8*)(cb + 2560 + n16 * 32 + swz);  // Kt dh 16-31

            #pragma unroll
            for (int qg = 0; qg < 2; ++qg) {
                f32x4 z = {};
                // swapped: C row = key position, col = query n16
                const f32x4 s0 = __builtin_amdgcn_mfma_f32_16x16x32_bf16(bk0, aq[qg], z, 0, 0, 0);
                const f32x4 s1 = __builtin_amdgcn_mfma_f32_16x16x32_bf16(bk1, aq[qg], z, 0, 0, 0);
                float e0[4], e1[4];
                #pragma unroll
                for (int r = 0; r < 4; ++r) {
                    e0[r] = __builtin_amdgcn_exp2f(s0[r]);   // key quad*8+r
                    e1[r] = __builtin_amdgcn_exp2f(s1[r]);   // key quad*8+4+r
                }
                union { bf16x8 v; unsigned u[4]; } pa;
                pa.u[0] = pk2bf(e0[0], e0[1]);
                pa.u[1] = pk2bf(e0[2], e0[3]);
                pa.u[2] = pk2bf(e1[0], e1[1]);
                pa.u[3] = pk2bf(e1[2], e1[3]);
                // swapped PV: C row = dh part, col = query n16
                acc[qg][0]   = __builtin_amdgcn_mfma_f32_16x16x32_bf16(bv0,  pa.v, acc[qg][0], 0, 0, 0);
                acc[qg][1]   = __builtin_amdgcn_mfma_f32_16x16x32_bf16(bv1,  pa.v, acc[qg][1], 0, 0, 0);
                lsacc[qg]    = __builtin_amdgcn_mfma_f32_16x16x32_bf16(ones, pa.v, lsacc[qg], 0, 0, 0);
                tsacc[qg][0] = __builtin_amdgcn_mfma_f32_16x16x32_bf16(bkt0, pa.v, tsacc[qg][0], 0, 0, 0);
                tsacc[qg][1] = __builtin_amdgcn_mfma_f32_16x16x32_bf16(bkt1, pa.v, tsacc[qg][1], 0, 0, 0);
            }
        }
    }

    const int bb = bh >> 2, h = bh & 3;
    short* dst = Oh + (size_t)kh * OSZ;
    #pragma unroll
    for (int qg = 0; qg < 2; ++qg) {
        const int q = qb + qg * 16 + n16;
        const float L = lsacc[qg][0];           // all rows equal
        // ts = q_scaled . (P.K^T): dot 8 local dh, then quad-reduce
        const short4 qa = *(const short4*)(Qb + ((size_t)bh * HW + q) * DH + quad * 4);
        const short4 qc = *(const short4*)(Qb + ((size_t)bh * HW + q) * DH + 16 + quad * 4);
        float ts = bf2f(qa.x) * tsacc[qg][0][0] + bf2f(qa.y) * tsacc[qg][0][1]
                 + bf2f(qa.z) * tsacc[qg][0][2] + bf2f(qa.w) * tsacc[qg][0][3]
                 + bf2f(qc.x) * tsacc[qg][1][0] + bf2f(qc.y) * tsacc[qg][1][1]
                 + bf2f(qc.z) * tsacc[qg][1][2] + bf2f(qc.w) * tsacc[qg][1][3];
        ts += __shfl_xor(ts, 16);
        ts += __shfl_xor(ts, 32);

        const float invl = 1.f / L;
        short* ap = dst + ((size_t)bb * HW + q) * HID + h * 32;
        short4 pk0 = {f2bf(acc[qg][0][0] * invl), f2bf(acc[qg][0][1] * invl),
                      f2bf(acc[qg][0][2] * invl), f2bf(acc[qg][0][3] * invl)};
        short4 pk1 = {f2bf(acc[qg][1][0] * invl), f2bf(acc[qg][1][1] * invl),
                      f2bf(acc[qg][1][2] * invl), f2bf(acc[qg][1][3] * invl)};
        *(short4*)(ap + quad * 4)      = pk0;   // dh quad*4 .. +3
        *(short4*)(ap + 16 + quad * 4) = pk1;   // dh 16+quad*4 .. +3
        if (quad == 0) {
            const size_t li = (size_t)(kh * 32 + bh) * HW + q;
            lsP[li] = L;
            tsP[li] = ts;
        }
    }
}

// ---------------------------------------------------------------------------
// Output conv with FUSED split-K combine + r12 XCD SWIZZLE: the 4 bm-blocks
// sharing one Oh-panel (128 px x 128 hid x 4 partials = 128 KB) colocate on
// one XCD. 576 = 8 xcd x 18 groups x 4 members; per-XCD 2.3 MB (< 4MB L2).
// Energy fold moves from blockIdx.y==0 to member m==0 (one per group).
// ---------------------------------------------------------------------------
__global__ __launch_bounds__(256, 2)
void conv_out(const short* __restrict__ A, const short* __restrict__ Oh,
              const float* __restrict__ lsP, const float* __restrict__ tsP,
              const float* __restrict__ bias, float* __restrict__ out0,
              float* __restrict__ E, int* __restrict__ ticket, int nblocks,
              float* __restrict__ edst)
{
    constexpr int KD = HID;                     // 128
    constexpr int NI = KD / 32;                 // 4 chunks == 4 heads
    // XCD swizzle: group g = (bn,b) Oh-panel, member m = bm
    const int flat = blockIdx.x + 18 * (blockIdx.y + 4 * blockIdx.z);
    const int xcd  = flat & 7, j = flat >> 3;   // j: 0..71
    const int g    = xcd + 8 * (j / 4);         // 0..143
    const int b    = g / 18;
    const int bn   = (g % 18) * 128;
    const int bmi  = j % 4;
    const int bm   = bmi * 64;
    const int t  = threadIdx.x;
    const int w  = t >> 6, lane = t & 63;
    const int n16 = lane & 15, quad = lane >> 4;

    __shared__ __align__(16) char csm[24576];   // 2 x (A 4KB | B 8KB)
    __shared__ float red[4];

    const int rL = lane >> 2, cswz = (lane & 3) ^ (rL & 3);
    const char* agl = (const char*)(A + (size_t)(bm + rL) * KD + cswz * 8);

    auto issueA = [&](int kc, int pbuf) {       // 4 x 1KB, waves 0-1
        char* base = csm + pbuf * 12288;
        if (w == 0) {
            gld16(agl + (size_t)(0 * 16 * KD + kc) * 2, base + 0 * 1024);
            gld16(agl + (size_t)(1 * 16 * KD + kc) * 2, base + 1 * 1024);
        } else if (w == 1) {
            gld16(agl + (size_t)(2 * 16 * KD + kc) * 2, base + 2 * 1024);
            gld16(agl + (size_t)(3 * 16 * KD + kc) * 2, base + 3 * 1024);
        }
    };

    // fused-combine B loader: 2 deposits/wave (16-pixel blocks w*2, w*2+1)
    auto loadB = [&](int ki, bf16x8 pk[2]) {
        const int kc = ki * 32;
        const int bh = b * NH + ki;             // chunk == head
        #pragma unroll
        for (int d = 0; d < 2; ++d) {
            const int blk = w * 2 + d;
            const int q = bn + blk * 16 + rL;
            float Ls[NSPLIT], sum = 0.f;
            #pragma unroll
            for (int kh = 0; kh < NSPLIT; ++kh) {
                Ls[kh] = lsP[(size_t)(kh * 32 + bh) * HW + q];
                sum += Ls[kh];
            }
            const float inv = 1.f / sum;
            float vv[8] = {};
            #pragma unroll
            for (int kh = 0; kh < NSPLIT; ++kh) {
                const float wk = Ls[kh] * inv;
                const bf16x8 o = *(const bf16x8*)(Oh + (size_t)kh * OSZ
                                    + ((size_t)b * HW + q) * HID + kc + cswz * 8);
                #pragma unroll
                for (int jj = 0; jj < 8; ++jj) vv[jj] += wk * bf2f(o[jj]);
            }
            union { bf16x8 v; unsigned u[4]; } c;
            #pragma unroll
            for (int i = 0; i < 4; ++i) c.u[i] = pk2bf(vv[2*i], vv[2*i+1]);
            pk[d] = c.v;
        }
    };
    auto writeB = [&](const bf16x8 pk[2], int pbuf) {
        char* base = csm + pbuf * 12288 + 4096;
        #pragma unroll
        for (int d = 0; d < 2; ++d) {
            const int blk = w * 2 + d;
            *(bf16x8*)(base + blk * 1024 + rL * 64 + (lane & 3) * 16) = pk[d];
        }
    };

    f32x4 acc[4][2] = {};
    const int rsw = (quad ^ (n16 & 3)) * 16;    // frag-read swizzle (bytes)

    bf16x8 bpk[2];
    loadB(0, bpk);
    issueA(0, 0);
    writeB(bpk, 0);
    for (int ki = 0; ki < NI; ++ki) {
        const int p = ki & 1;
        __syncthreads();                        // chunk ki landed (A DMA + B writes)
        if (ki + 1 < NI) { loadB(ki + 1, bpk); issueA((ki + 1) * 32, p ^ 1); }

        const char* Ap = csm + p * 12288;
        const char* Bp = Ap + 4096;
        bf16x8 am[4], bq[2];
        #pragma unroll
        for (int tm = 0; tm < 4; ++tm)
            am[tm] = *(const bf16x8*)(Ap + tm * 1024 + n16 * 64 + rsw);
        #pragma unroll
        for (int jj = 0; jj < 2; ++jj)
            bq[jj] = *(const bf16x8*)(Bp + (w * 2 + jj) * 1024 + n16 * 64 + rsw);
        #pragma unroll
        for (int tm = 0; tm < 4; ++tm)
            #pragma unroll
            for (int jj = 0; jj < 2; ++jj)
                acc[tm][jj] = __builtin_amdgcn_mfma_f32_16x16x32_bf16(am[tm], bq[jj], acc[tm][jj], 0, 0, 0);

        if (ki + 1 < NI) writeB(bpk, p ^ 1);    // after this chunk's frag reads
    }

    float e = 0.f;
    #pragma unroll
    for (int tm = 0; tm < 4; ++tm) {
        const int o0 = bm + tm * 16 + quad * 4;
        const float4 bb = *(const float4*)(bias + o0);
        #pragma unroll
        for (int jj = 0; jj < 2; ++jj) {
            const int s = bn + (w * 2 + jj) * 16 + n16;
            float v[4] = {acc[tm][jj][0] + bb.x, acc[tm][jj][1] + bb.y,
                          acc[tm][jj][2] + bb.z, acc[tm][jj][3] + bb.w};
            e -= 0.5f * (v[0]*v[0] + v[1]*v[1] + v[2]*v[2] + v[3]*v[3]);
            #pragma unroll
            for (int r = 0; r < 4; ++r)
                out0[((size_t)b * NC + o0 + r) * HW + s] = v[r];
        }
    }

    if (bmi == 0) {                             // attention energy, once per (b,q,h)
        const int q = bn + (t & 127);
        #pragma unroll
        for (int jj = 0; jj < 2; ++jj) {
            const int h = (t >> 7) * 2 + jj;
            const int bh = b * NH + h;
            float L = 0.f, T = 0.f;
            #pragma unroll
            for (int kh = 0; kh < NSPLIT; ++kh) {
                L += lsP[(size_t)(kh * 32 + bh) * HW + q];
                T += tsP[(size_t)(kh * 32 + bh) * HW + q];
            }
            e += (LN2 * T) / L - __logf(L);
        }
    }

    #pragma unroll
    for (int off = 32; off > 0; off >>= 1) e += __shfl_down(e, off);
    if (lane == 0) red[w] = e;
    __syncthreads();
    if (t == 0) {
        atomicAdd(E, red[0] + red[1] + red[2] + red[3]);
        __threadfence();
        const int prev = atomicAdd(ticket, 1);
        if (prev == nblocks - 1) {
            __threadfence();
            edst[0] = atomicAdd(E, 0.f);
        }
    }
}

// ---------------------------------------------------------------------------
extern "C" void kernel_launch(void* const* d_in, const int* in_sizes, int n_in,
                              void* d_out, int out_size, void* d_ws, size_t ws_size,
                              hipStream_t stream) {
    const float* x     = (const float*)d_in[0];
    const float* w_qkv = (const float*)d_in[1];
    const float* b_qkv = (const float*)d_in[2];
    const float* w_out = (const float*)d_in[3];
    const float* b_out = (const float*)d_in[4];
    float* out = (float*)d_out;

    float* wsf    = (float*)d_ws;
    float* E      = wsf;                               // [0] energy accumulator
    int*   ticket = (int*)d_ws + 1;                    // [1] conv_out ticket
    short* Xt   = (short*)(wsf + 16);                  // bf16 [b][s][c]
    short* Wq   = Xt + (size_t)NB * HW * NC;           // bf16 [384][256]
    short* Wo   = Wq + 384 * 256;                      // bf16 [256][128]
    short* Qb   = Wo + 256 * 128;                      // bf16 [bh][s][dh] (xSCALE*log2e)
    short* Kb   = Qb + (size_t)NB * NH * HW * DH;      // bf16 [bh][s'][dh], sigma-permuted
    short* Ktb  = Kb + (size_t)NB * NH * HW * DH;      // bf16 [bh][dh][s] (K^T)
    short* Vb   = Ktb + (size_t)NB * NH * HW * DH;     // bf16 [bh][dh][s]
    short* Oh   = Vb + (size_t)NB * NH * HW * DH;      // bf16 [NSPLIT][b][s][hid]
    float* lsP  = (float*)(Oh + NSPLIT * OSZ);         // f32 [NSPLIT][32][HW]
    float* tsP  = lsP + NSPLIT * 32 * HW;              // f32 [NSPLIT][32][HW]

    prep<<<dim3(HW / 64, NC / 64, NB + 1), 256, 0, stream>>>(
        x, w_qkv, w_out, Xt, Wq, Wo, wsf);
    conv_qkv<<<dim3(18, 6, NB), 256, 0, stream>>>(
        Wq, Xt, b_qkv, Qb, Kb, Ktb, Vb, E);
    flashsplit<<<dim3(HW / 128, NB * NH, NSPLIT), 256, 0, stream>>>(
        Qb, Kb, Ktb, Vb, Oh, lsP, tsP);
    conv_out<<<dim3(18, 4, NB), 256, 0, stream>>>(
        Wo, Oh, lsP, tsP, b_out, out, E, ticket, 18 * 4 * NB,
        out + (size_t)NB * NC * HW);
}